// Round 1
// baseline (719.121 us; speedup 1.0000x reference)
//
#include <hip/hip_runtime.h>

typedef unsigned char u8;

// ---------------- K0: codebook row norms + zero loss accumulator ----------------
__global__ __launch_bounds__(256) void k0_cnorm(const float* __restrict__ cb,
                                                float* __restrict__ cnorm,
                                                float* __restrict__ lossacc) {
    int g = blockIdx.x * 256 + threadIdx.x;
    if (g < 1024) {
        float s = 0.f;
#pragma unroll
        for (int d = 0; d < 25; ++d) { float v = cb[g * 25 + d]; s += v * v; }
        cnorm[g] = s;
    }
    if (g == 0) lossacc[0] = 0.f;   // ws is poisoned 0xAA each call
}

// ---------------- K1: enc1 conv3x3(3->32)+relu+maxpool2x2 (keep argmax) ----------------
__global__ __launch_bounds__(256) void k1_enc1(const float* __restrict__ x,
                                               const float* __restrict__ w,
                                               const float* __restrict__ bias,
                                               float* __restrict__ p1,
                                               u8* __restrict__ idx1) {
    const int img = blockIdx.x;
    const int tid = threadIdx.x;
    __shared__ float xs[1200];   // [3][20][20]
    __shared__ float ws[864];    // [32][3][3][3]
    __shared__ float bs[32];
    for (int i = tid; i < 1200; i += 256) xs[i] = x[img * 1200 + i];
    for (int i = tid; i < 864; i += 256) ws[i] = w[i];
    if (tid < 32) bs[tid] = bias[tid];
    __syncthreads();
    for (int o = tid; o < 3200; o += 256) {
        int c = o / 100;
        int rem = o % 100;
        int r = rem / 10, cc = rem % 10;
        float acc[4];
        acc[0] = acc[1] = acc[2] = acc[3] = bs[c];
        for (int ci = 0; ci < 3; ++ci) {
            float win[4][4];
#pragma unroll
            for (int wy = 0; wy < 4; ++wy) {
                int yy = 2 * r - 1 + wy;
#pragma unroll
                for (int wx = 0; wx < 4; ++wx) {
                    int xx = 2 * cc - 1 + wx;
                    win[wy][wx] = (yy >= 0 && yy < 20 && xx >= 0 && xx < 20)
                                      ? xs[ci * 400 + yy * 20 + xx] : 0.f;
                }
            }
            const float* wp = &ws[(c * 3 + ci) * 9];
            float wr[9];
#pragma unroll
            for (int k = 0; k < 9; ++k) wr[k] = wp[k];
#pragma unroll
            for (int q = 0; q < 4; ++q) {
                int dr = q >> 1, dc = q & 1;
#pragma unroll
                for (int ky = 0; ky < 3; ++ky)
#pragma unroll
                    for (int kx = 0; kx < 3; ++kx)
                        acc[q] += win[dr + ky][dc + kx] * wr[ky * 3 + kx];
            }
        }
        // relu then pool; jnp.argmax takes FIRST max on ties -> strict >
        float best = -1.f; int bi = 0;
#pragma unroll
        for (int q = 0; q < 4; ++q) {
            float v = fmaxf(acc[q], 0.f);
            if (v > best) { best = v; bi = q; }
        }
        p1[img * 3200 + o] = best;
        idx1[img * 3200 + o] = (u8)bi;
    }
}

// ---------------- K2: enc2 conv3x3(32->96)+relu+maxpool2x2 ----------------
__global__ __launch_bounds__(256) void k2_enc2(const float* __restrict__ p1,
                                               const float* __restrict__ w,   // [96][32][9]
                                               const float* __restrict__ bias,
                                               float* __restrict__ z,
                                               u8* __restrict__ idx2) {
    const int img = blockIdx.x;
    const int tid = threadIdx.x;
    __shared__ float p1s[3200];        // [32][10][10]
    __shared__ float w2s[6912];        // [96][8][9] ci-chunk
    for (int i = tid; i < 3200; i += 256) p1s[i] = p1[img * 3200 + i];
    const int pos = tid % 25;
    const int ocg = tid / 25;          // active if < 8 (12 oc each)
    const int r = pos / 5, c = pos % 5;
    const bool active = (ocg < 8);
    float acc[12][4];
#pragma unroll
    for (int j = 0; j < 12; ++j)
#pragma unroll
        for (int q = 0; q < 4; ++q) acc[j][q] = 0.f;
    for (int chunk = 0; chunk < 4; ++chunk) {
        __syncthreads();
        for (int i = tid; i < 6912; i += 256) {
            int oc = i / 72, rr = i % 72;
            int cc2 = rr / 9, kk = rr % 9;
            w2s[i] = w[(oc * 32 + chunk * 8 + cc2) * 9 + kk];
        }
        __syncthreads();
        if (active) {
            for (int cil = 0; cil < 8; ++cil) {
                int ci = chunk * 8 + cil;
                float win[4][4];
#pragma unroll
                for (int wy = 0; wy < 4; ++wy) {
                    int yy = 2 * r - 1 + wy;
#pragma unroll
                    for (int wx = 0; wx < 4; ++wx) {
                        int xx = 2 * c - 1 + wx;
                        win[wy][wx] = (yy >= 0 && yy < 10 && xx >= 0 && xx < 10)
                                          ? p1s[ci * 100 + yy * 10 + xx] : 0.f;
                    }
                }
#pragma unroll
                for (int j = 0; j < 12; ++j) {
                    const float* wp = &w2s[(ocg * 12 + j) * 72 + cil * 9];
                    float wr[9];
#pragma unroll
                    for (int k = 0; k < 9; ++k) wr[k] = wp[k];
#pragma unroll
                    for (int q = 0; q < 4; ++q) {
                        int dr = q >> 1, dc = q & 1;
#pragma unroll
                        for (int ky = 0; ky < 3; ++ky)
#pragma unroll
                            for (int kx = 0; kx < 3; ++kx)
                                acc[j][q] += win[dr + ky][dc + kx] * wr[ky * 3 + kx];
                    }
                }
            }
        }
    }
    if (active) {
#pragma unroll
        for (int j = 0; j < 12; ++j) {
            int oc = ocg * 12 + j;
            float bb = bias[oc];
            float best = -1.f; int bi = 0;
#pragma unroll
            for (int q = 0; q < 4; ++q) {
                float v = fmaxf(acc[j][q] + bb, 0.f);
                if (v > best) { best = v; bi = q; }
            }
            z[img * 2400 + oc * 25 + pos] = best;
            idx2[img * 2400 + oc * 25 + pos] = (u8)bi;
        }
    }
}

// ---------------- K3a: pre 1x1 conv (96->128) ----------------
__global__ __launch_bounds__(256) void k3a_pre(const float* __restrict__ z,
                                               const float* __restrict__ w,   // [128][96]
                                               const float* __restrict__ bias,
                                               float* __restrict__ vq) {
    const int img = blockIdx.x;
    const int tid = threadIdx.x;
    __shared__ float zs[2400];       // [96][25]
    __shared__ float pws[12288];     // [128][96]
    for (int i = tid; i < 2400; i += 256) zs[i] = z[img * 2400 + i];
    for (int i = tid; i < 12288; i += 256) pws[i] = w[i];
    __syncthreads();
    const int sg = tid % 5;
    const int eg = tid / 5;          // active if < 32
    if (eg >= 32) return;            // no more barriers below
    const int e0 = eg * 4, s0 = sg * 5;
    float acc[4][5];
#pragma unroll
    for (int j = 0; j < 4; ++j)
#pragma unroll
        for (int ss = 0; ss < 5; ++ss) acc[j][ss] = 0.f;
    for (int ci = 0; ci < 96; ++ci) {
        float zv[5];
#pragma unroll
        for (int ss = 0; ss < 5; ++ss) zv[ss] = zs[ci * 25 + s0 + ss];
#pragma unroll
        for (int j = 0; j < 4; ++j) {
            float wv = pws[(e0 + j) * 96 + ci];
#pragma unroll
            for (int ss = 0; ss < 5; ++ss) acc[j][ss] += wv * zv[ss];
        }
    }
#pragma unroll
    for (int j = 0; j < 4; ++j) {
        float bb = bias[e0 + j];
#pragma unroll
        for (int ss = 0; ss < 5; ++ss)
            vq[img * 3200 + (e0 + j) * 25 + s0 + ss] = acc[j][ss] + bb;
    }
}

// ---------------- K3b: VQ argmin over 1024 codes + loss partials ----------------
// block = 64 tokens; thread = 4 tokens (regs) x 64 codes; 16 sub-slices reduced in LDS.
__global__ __launch_bounds__(256) void k3b_vq(const float* __restrict__ vq,
                                              const float* __restrict__ cb,
                                              const float* __restrict__ cnorm,
                                              int* __restrict__ vqidx,
                                              float* __restrict__ lossacc) {
    const int tb = blockIdx.x * 64;     // 2048 blocks
    const int tid = threadIdx.x;
    __shared__ __align__(16) float fs[64 * 28];
    __shared__ __align__(16) float cs[128 * 28];
    __shared__ float cn[128];
    __shared__ float rs[64 * 16];
    __shared__ int   rk[64 * 16];
    for (int i = tid; i < 64 * 28; i += 256) {
        int t = i / 28, d = i % 28;
        fs[i] = (d < 25) ? vq[(tb + t) * 25 + d] : 0.f;
    }
    __syncthreads();
    const int quad = tid & 15, sub = tid >> 4;
    const int t0 = quad * 4;
    float f[4][28];
#pragma unroll
    for (int t = 0; t < 4; ++t)
#pragma unroll
        for (int d = 0; d < 28; ++d) f[t][d] = fs[(t0 + t) * 28 + d];
    float best[4] = {1e30f, 1e30f, 1e30f, 1e30f};
    int bk[4] = {0, 0, 0, 0};
    for (int ch = 0; ch < 8; ++ch) {
        __syncthreads();
        for (int i = tid; i < 128 * 28; i += 256) {
            int k = i / 28, d = i % 28;
            cs[i] = (d < 25) ? cb[(ch * 128 + k) * 25 + d] : 0.f;
        }
        if (tid < 128) cn[tid] = cnorm[ch * 128 + tid];
        __syncthreads();
        for (int j = 0; j < 8; ++j) {
            int kk = sub * 8 + ((j + sub) & 7);   // bank-staggered across subs
            const float* crow = &cs[kk * 28];
            float a0 = 0.f, a1 = 0.f, a2 = 0.f, a3 = 0.f;
#pragma unroll
            for (int i = 0; i < 7; ++i) {
                float4 c4 = *(const float4*)(crow + i * 4);
                a0 += f[0][i*4+0]*c4.x + f[0][i*4+1]*c4.y + f[0][i*4+2]*c4.z + f[0][i*4+3]*c4.w;
                a1 += f[1][i*4+0]*c4.x + f[1][i*4+1]*c4.y + f[1][i*4+2]*c4.z + f[1][i*4+3]*c4.w;
                a2 += f[2][i*4+0]*c4.x + f[2][i*4+1]*c4.y + f[2][i*4+2]*c4.z + f[2][i*4+3]*c4.w;
                a3 += f[3][i*4+0]*c4.x + f[3][i*4+1]*c4.y + f[3][i*4+2]*c4.z + f[3][i*4+3]*c4.w;
            }
            int kg = ch * 128 + kk;
            float cnk = cn[kk];
            float s0 = cnk - 2.f * a0;
            float s1 = cnk - 2.f * a1;
            float s2 = cnk - 2.f * a2;
            float s3 = cnk - 2.f * a3;
            if (s0 < best[0] || (s0 == best[0] && kg < bk[0])) { best[0] = s0; bk[0] = kg; }
            if (s1 < best[1] || (s1 == best[1] && kg < bk[1])) { best[1] = s1; bk[1] = kg; }
            if (s2 < best[2] || (s2 == best[2] && kg < bk[2])) { best[2] = s2; bk[2] = kg; }
            if (s3 < best[3] || (s3 == best[3] && kg < bk[3])) { best[3] = s3; bk[3] = kg; }
        }
    }
#pragma unroll
    for (int t = 0; t < 4; ++t) {
        rs[(t0 + t) * 16 + sub] = best[t];
        rk[(t0 + t) * 16 + sub] = bk[t];
    }
    __syncthreads();
    float dloc = 0.f;
    if (tid < 64) {
        float bs2 = 1e30f; int bkk = 1 << 30;
        for (int u = 0; u < 16; ++u) {
            float s = rs[tid * 16 + u]; int k = rk[tid * 16 + u];
            if (s < bs2 || (s == bs2 && k < bkk)) { bs2 = s; bkk = k; }
        }
        vqidx[tb + tid] = bkk;
        float ff = 0.f;
#pragma unroll
        for (int d = 0; d < 28; ++d) { float v = fs[tid * 28 + d]; ff += v * v; }
        dloc = ff + bs2;   // = ||f - c_best||^2
    }
    __syncthreads();
    if (tid < 64) rs[tid] = dloc;
    __syncthreads();
    if (tid == 0) {
        float s = 0.f;
        for (int t = 0; t < 64; ++t) s += rs[t];
        atomicAdd(lossacc, s);
    }
}

// ---------------- Kf: finalize loss ----------------
__global__ void kf_loss(const float* __restrict__ lossacc, float* __restrict__ out) {
    out[0] = 0.25f * lossacc[0] / 3276800.0f;   // mean over B*128*25
}

// ---------------- K5: gather codebook, trans 1x1 (128->96) + pose head ----------------
__global__ __launch_bounds__(256) void k5_latent_pose(
    const int* __restrict__ vqidx, const float* __restrict__ cb,
    const float* __restrict__ tw, const float* __restrict__ tbb,
    const float* __restrict__ w1, const float* __restrict__ b1,
    const float* __restrict__ w2, const float* __restrict__ b2,
    float* __restrict__ latg, float* __restrict__ outkp) {
    const int img = blockIdx.x;
    const int tid = threadIdx.x;
    __shared__ int idxs[128];
    __shared__ float zr[128 * 26];   // padded
    __shared__ float lat[2400];      // [96][25] = feat layout
    __shared__ float ps[256];        // 8 segs x 32
    __shared__ float hs[32];
    if (tid < 128) idxs[tid] = vqidx[img * 128 + tid];
    __syncthreads();
    for (int i = tid; i < 3200; i += 256) {
        int e = i / 25, d = i % 25;
        zr[e * 26 + d] = cb[idxs[e] * 25 + d];
    }
    __syncthreads();
    const int sg = tid % 5, og = tid / 5;   // active og<24 (4 oc x 5 s each)
    if (og < 24) {
        const int oc0 = og * 4, s0 = sg * 5;
        float acc[4][5];
#pragma unroll
        for (int j = 0; j < 4; ++j)
#pragma unroll
            for (int ss = 0; ss < 5; ++ss) acc[j][ss] = 0.f;
        for (int e = 0; e < 128; ++e) {
            float zv[5];
#pragma unroll
            for (int ss = 0; ss < 5; ++ss) zv[ss] = zr[e * 26 + s0 + ss];
#pragma unroll
            for (int j = 0; j < 4; ++j) {
                float wv = tw[e * 96 + oc0 + j];
#pragma unroll
                for (int ss = 0; ss < 5; ++ss) acc[j][ss] += wv * zv[ss];
            }
        }
#pragma unroll
        for (int j = 0; j < 4; ++j) {
            float bb = tbb[oc0 + j];
#pragma unroll
            for (int ss = 0; ss < 5; ++ss) {
                float v = acc[j][ss] + bb;
                lat[(oc0 + j) * 25 + s0 + ss] = v;
                latg[img * 2400 + (oc0 + j) * 25 + s0 + ss] = v;
            }
        }
    }
    __syncthreads();
    // pose hidden partials: 8 segments x 32 hidden
    {
        const int seg = tid >> 5, jj = tid & 31;
        float s = 0.f;
        const int i0 = seg * 300;
        for (int i = i0; i < i0 + 300; ++i) s += lat[i] * w1[i * 32 + jj];
        ps[seg * 32 + jj] = s;
    }
    __syncthreads();
    if (tid < 32) {
        float h = b1[tid];
#pragma unroll
        for (int s2 = 0; s2 < 8; ++s2) h += ps[s2 * 32 + tid];
        hs[tid] = fmaxf(h, 0.f);
    }
    __syncthreads();
    if (tid < 36) {
        float kp = b2[tid];
#pragma unroll
        for (int m = 0; m < 32; ++m) kp += hs[m] * w2[m * 36 + tid];
        outkp[img * 36 + tid] = kp;
    }
}

// ---------------- K6: unpool(idx2) + dec1 conv3x3(96->32)+relu ----------------
__global__ __launch_bounds__(256) void k6_dec1(const float* __restrict__ latg,
                                               const u8* __restrict__ idx2,
                                               const float* __restrict__ w,   // [32][96][9]
                                               const float* __restrict__ bias,
                                               float* __restrict__ d1) {
    const int img = blockIdx.x;
    const int tid = threadIdx.x;
    __shared__ float u2s[9600];    // [96][10][10]
    __shared__ float w1s[4608];    // [32][16][9] ci-chunk
    for (int i = tid; i < 9600; i += 256) u2s[i] = 0.f;
    __syncthreads();
    for (int i = tid; i < 2400; i += 256) {
        int ci = i / 25, s = i % 25;
        int r = s / 5, c = s % 5;
        int q = idx2[img * 2400 + i];
        u2s[ci * 100 + (2 * r + (q >> 1)) * 10 + 2 * c + (q & 1)] = latg[img * 2400 + i];
    }
    const int quad = tid % 25, ocg = tid / 25;  // active ocg<8 (4 oc each)
    const int qr = quad / 5, qc = quad % 5;
    const int y0 = 2 * qr, x0 = 2 * qc;
    float acc[4][4];
#pragma unroll
    for (int j = 0; j < 4; ++j)
#pragma unroll
        for (int q = 0; q < 4; ++q) acc[j][q] = 0.f;
    for (int chunk = 0; chunk < 6; ++chunk) {
        __syncthreads();
        for (int i = tid; i < 4608; i += 256) {
            int oc = i / 144, rr = i % 144;
            int cc2 = rr / 9, kk = rr % 9;
            w1s[i] = w[(oc * 96 + chunk * 16 + cc2) * 9 + kk];
        }
        __syncthreads();
        if (ocg < 8) {
            for (int cil = 0; cil < 16; ++cil) {
                int ci = chunk * 16 + cil;
                float win[4][4];
#pragma unroll
                for (int wy = 0; wy < 4; ++wy) {
                    int yy = y0 - 1 + wy;
#pragma unroll
                    for (int wx = 0; wx < 4; ++wx) {
                        int xx = x0 - 1 + wx;
                        win[wy][wx] = (yy >= 0 && yy < 10 && xx >= 0 && xx < 10)
                                          ? u2s[ci * 100 + yy * 10 + xx] : 0.f;
                    }
                }
#pragma unroll
                for (int j = 0; j < 4; ++j) {
                    const float* wp = &w1s[(ocg * 4 + j) * 144 + cil * 9];
                    float wr[9];
#pragma unroll
                    for (int k = 0; k < 9; ++k) wr[k] = wp[k];
#pragma unroll
                    for (int q = 0; q < 4; ++q) {
                        int dr = q >> 1, dc = q & 1;
#pragma unroll
                        for (int ky = 0; ky < 3; ++ky)
#pragma unroll
                            for (int kx = 0; kx < 3; ++kx)
                                acc[j][q] += win[dr + ky][dc + kx] * wr[ky * 3 + kx];
                    }
                }
            }
        }
    }
    if (ocg < 8) {
#pragma unroll
        for (int j = 0; j < 4; ++j) {
            int oc = ocg * 4 + j;
            float bb = bias[oc];
#pragma unroll
            for (int q = 0; q < 4; ++q) {
                int dr = q >> 1, dc = q & 1;
                d1[img * 3200 + oc * 100 + (y0 + dr) * 10 + (x0 + dc)] =
                    fmaxf(acc[j][q] + bb, 0.f);
            }
        }
    }
}

// ---------------- K7: unpool(idx1) + dec2 conv3x3(32->3) -> r_x ----------------
__global__ __launch_bounds__(256) void k7_dec2(const float* __restrict__ d1,
                                               const u8* __restrict__ idx1,
                                               const float* __restrict__ w,   // [3][32][9]
                                               const float* __restrict__ bias,
                                               float* __restrict__ rx) {
    const int img = blockIdx.x;
    const int tid = threadIdx.x;
    __shared__ float u1s[12800];   // [32][20][20]
    __shared__ float wss[864];
    __shared__ float bss[3];
    for (int i = tid; i < 12800; i += 256) u1s[i] = 0.f;
    for (int i = tid; i < 864; i += 256) wss[i] = w[i];
    if (tid < 3) bss[tid] = bias[tid];
    __syncthreads();
    for (int i = tid; i < 3200; i += 256) {
        int c = i / 100, s = i % 100;
        int r = s / 10, cc = s % 10;
        int q = idx1[img * 3200 + i];
        u1s[c * 400 + (2 * r + (q >> 1)) * 20 + 2 * cc + (q & 1)] = d1[img * 3200 + i];
    }
    __syncthreads();
    if (tid < 200) {
        const int y = tid / 10, px = tid % 10;
        const int x0 = px * 2;
        float acc[3][2] = {{0.f, 0.f}, {0.f, 0.f}, {0.f, 0.f}};
        for (int ci = 0; ci < 32; ++ci) {
            float win[3][4];
#pragma unroll
            for (int wy = 0; wy < 3; ++wy) {
                int yy = y - 1 + wy;
#pragma unroll
                for (int wx = 0; wx < 4; ++wx) {
                    int xx = x0 - 1 + wx;
                    win[wy][wx] = (yy >= 0 && yy < 20 && xx >= 0 && xx < 20)
                                      ? u1s[ci * 400 + yy * 20 + xx] : 0.f;
                }
            }
#pragma unroll
            for (int oc = 0; oc < 3; ++oc) {
                const float* wp = &wss[(oc * 32 + ci) * 9];
                float wr[9];
#pragma unroll
                for (int k = 0; k < 9; ++k) wr[k] = wp[k];
#pragma unroll
                for (int ky = 0; ky < 3; ++ky)
#pragma unroll
                    for (int kx = 0; kx < 3; ++kx) {
                        acc[oc][0] += win[ky][kx] * wr[ky * 3 + kx];
                        acc[oc][1] += win[ky][kx + 1] * wr[ky * 3 + kx];
                    }
            }
        }
#pragma unroll
        for (int oc = 0; oc < 3; ++oc) {
#pragma unroll
            for (int dx = 0; dx < 2; ++dx)
                rx[img * 1200 + oc * 400 + y * 20 + x0 + dx] = acc[oc][dx] + bss[oc];
        }
    }
}

extern "C" void kernel_launch(void* const* d_in, const int* in_sizes, int n_in,
                              void* d_out, int out_size, void* d_ws, size_t ws_size,
                              hipStream_t stream) {
    const float* x   = (const float*)d_in[0];
    const float* e1w = (const float*)d_in[1];
    const float* e1b = (const float*)d_in[2];
    const float* e2w = (const float*)d_in[3];
    const float* e2b = (const float*)d_in[4];
    const float* prw = (const float*)d_in[5];
    const float* prb = (const float*)d_in[6];
    const float* cb  = (const float*)d_in[7];
    const float* tw  = (const float*)d_in[8];
    const float* tbb = (const float*)d_in[9];
    const float* d1w = (const float*)d_in[10];
    const float* d1b = (const float*)d_in[11];
    const float* d2w = (const float*)d_in[12];
    const float* d2b = (const float*)d_in[13];
    const float* hw1 = (const float*)d_in[14];
    const float* hb1 = (const float*)d_in[15];
    const float* hw2 = (const float*)d_in[16];
    const float* hb2 = (const float*)d_in[17];
    float* out = (float*)d_out;

    // workspace layout (fp32 unless noted); buffers reused where lifetimes allow
    float* ws      = (float*)d_ws;
    float* cnorm   = ws;                        // 1024
    float* lossacc = cnorm + 1024;              // 4
    float* p1      = lossacc + 4;               // 3,276,800 (reused as latent after K2)
    float* z       = p1 + 3276800;              // 2,457,600
    float* vq      = z + 2457600;               // 3,276,800 (reused as d1 after K3b)
    int*   vqidx   = (int*)(vq + 3276800);      // 131,072
    u8*    idx1    = (u8*)(vqidx + 131072);     // 3,276,800 bytes
    u8*    idx2    = idx1 + 3276800;            // 2,457,600 bytes
    float* latent  = p1;
    float* d1buf   = vq;

    float* rx  = out + 1;
    float* okp = out + 1 + 1228800;

    k0_cnorm<<<4, 256, 0, stream>>>(cb, cnorm, lossacc);
    k1_enc1<<<1024, 256, 0, stream>>>(x, e1w, e1b, p1, idx1);
    k2_enc2<<<1024, 256, 0, stream>>>(p1, e2w, e2b, z, idx2);
    k3a_pre<<<1024, 256, 0, stream>>>(z, prw, prb, vq);
    k3b_vq<<<2048, 256, 0, stream>>>(vq, cb, cnorm, vqidx, lossacc);
    kf_loss<<<1, 1, 0, stream>>>(lossacc, out);
    k5_latent_pose<<<1024, 256, 0, stream>>>(vqidx, cb, tw, tbb, hw1, hb1, hw2, hb2,
                                             latent, okp);
    k6_dec1<<<1024, 256, 0, stream>>>(latent, idx2, d1w, d1b, d1buf);
    k7_dec2<<<1024, 256, 0, stream>>>(d1buf, idx1, d2w, d2b, rx);
}

// Round 2
// 612.631 us; speedup vs baseline: 1.1738x; 1.1738x over previous
//
#include <hip/hip_runtime.h>

typedef unsigned char u8;

// ---------------- K0: codebook row norms + zero loss accumulator ----------------
__global__ __launch_bounds__(256) void k0_cnorm(const float* __restrict__ cb,
                                                float* __restrict__ cnorm,
                                                float* __restrict__ lossacc) {
    int g = blockIdx.x * 256 + threadIdx.x;
    if (g < 1024) {
        float s = 0.f;
#pragma unroll
        for (int d = 0; d < 25; ++d) { float v = cb[g * 25 + d]; s += v * v; }
        cnorm[g] = s;
    }
    if (g == 0) lossacc[0] = 0.f;   // ws is poisoned 0xAA each call
}

// ---------------- K1: enc1 conv3x3(3->32)+relu+maxpool2x2 (keep argmax) ----------------
__global__ __launch_bounds__(256) void k1_enc1(const float* __restrict__ x,
                                               const float* __restrict__ w,
                                               const float* __restrict__ bias,
                                               float* __restrict__ p1,
                                               u8* __restrict__ idx1) {
    const int img = blockIdx.x;
    const int tid = threadIdx.x;
    __shared__ float xs[1200];   // [3][20][20]
    __shared__ float ws[864];    // [32][3][3][3]
    __shared__ float bs[32];
    for (int i = tid; i < 1200; i += 256) xs[i] = x[img * 1200 + i];
    for (int i = tid; i < 864; i += 256) ws[i] = w[i];
    if (tid < 32) bs[tid] = bias[tid];
    __syncthreads();
    for (int o = tid; o < 3200; o += 256) {
        int c = o / 100;
        int rem = o % 100;
        int r = rem / 10, cc = rem % 10;
        float acc[4];
        acc[0] = acc[1] = acc[2] = acc[3] = bs[c];
        for (int ci = 0; ci < 3; ++ci) {
            float win[4][4];
#pragma unroll
            for (int wy = 0; wy < 4; ++wy) {
                int yy = 2 * r - 1 + wy;
#pragma unroll
                for (int wx = 0; wx < 4; ++wx) {
                    int xx = 2 * cc - 1 + wx;
                    win[wy][wx] = (yy >= 0 && yy < 20 && xx >= 0 && xx < 20)
                                      ? xs[ci * 400 + yy * 20 + xx] : 0.f;
                }
            }
            const float* wp = &ws[(c * 3 + ci) * 9];
            float wr[9];
#pragma unroll
            for (int k = 0; k < 9; ++k) wr[k] = wp[k];
#pragma unroll
            for (int q = 0; q < 4; ++q) {
                int dr = q >> 1, dc = q & 1;
#pragma unroll
                for (int ky = 0; ky < 3; ++ky)
#pragma unroll
                    for (int kx = 0; kx < 3; ++kx)
                        acc[q] += win[dr + ky][dc + kx] * wr[ky * 3 + kx];
            }
        }
        // relu then pool; jnp.argmax takes FIRST max on ties -> strict >
        float best = -1.f; int bi = 0;
#pragma unroll
        for (int q = 0; q < 4; ++q) {
            float v = fmaxf(acc[q], 0.f);
            if (v > best) { best = v; bi = q; }
        }
        p1[img * 3200 + o] = best;
        idx1[img * 3200 + o] = (u8)bi;
    }
}

// ---------------- K2: enc2 conv3x3(32->96)+relu+maxpool2x2 ----------------
__global__ __launch_bounds__(256) void k2_enc2(const float* __restrict__ p1,
                                               const float* __restrict__ w,   // [96][32][9]
                                               const float* __restrict__ bias,
                                               float* __restrict__ z,
                                               u8* __restrict__ idx2) {
    const int img = blockIdx.x;
    const int tid = threadIdx.x;
    __shared__ float p1s[3200];        // [32][10][10]
    __shared__ float w2s[6912];        // [96][8][9] ci-chunk
    for (int i = tid; i < 3200; i += 256) p1s[i] = p1[img * 3200 + i];
    const int pos = tid % 25;
    const int ocg = tid / 25;          // active if < 8 (12 oc each)
    const int r = pos / 5, c = pos % 5;
    const bool active = (ocg < 8);
    float acc[12][4];
#pragma unroll
    for (int j = 0; j < 12; ++j)
#pragma unroll
        for (int q = 0; q < 4; ++q) acc[j][q] = 0.f;
    for (int chunk = 0; chunk < 4; ++chunk) {
        __syncthreads();
        for (int i = tid; i < 6912; i += 256) {
            int oc = i / 72, rr = i % 72;
            int cc2 = rr / 9, kk = rr % 9;
            w2s[i] = w[(oc * 32 + chunk * 8 + cc2) * 9 + kk];
        }
        __syncthreads();
        if (active) {
            for (int cil = 0; cil < 8; ++cil) {
                int ci = chunk * 8 + cil;
                float win[4][4];
#pragma unroll
                for (int wy = 0; wy < 4; ++wy) {
                    int yy = 2 * r - 1 + wy;
#pragma unroll
                    for (int wx = 0; wx < 4; ++wx) {
                        int xx = 2 * c - 1 + wx;
                        win[wy][wx] = (yy >= 0 && yy < 10 && xx >= 0 && xx < 10)
                                          ? p1s[ci * 100 + yy * 10 + xx] : 0.f;
                    }
                }
#pragma unroll
                for (int j = 0; j < 12; ++j) {
                    const float* wp = &w2s[(ocg * 12 + j) * 72 + cil * 9];
                    float wr[9];
#pragma unroll
                    for (int k = 0; k < 9; ++k) wr[k] = wp[k];
#pragma unroll
                    for (int q = 0; q < 4; ++q) {
                        int dr = q >> 1, dc = q & 1;
#pragma unroll
                        for (int ky = 0; ky < 3; ++ky)
#pragma unroll
                            for (int kx = 0; kx < 3; ++kx)
                                acc[j][q] += win[dr + ky][dc + kx] * wr[ky * 3 + kx];
                    }
                }
            }
        }
    }
    if (active) {
#pragma unroll
        for (int j = 0; j < 12; ++j) {
            int oc = ocg * 12 + j;
            float bb = bias[oc];
            float best = -1.f; int bi = 0;
#pragma unroll
            for (int q = 0; q < 4; ++q) {
                float v = fmaxf(acc[j][q] + bb, 0.f);
                if (v > best) { best = v; bi = q; }
            }
            z[img * 2400 + oc * 25 + pos] = best;
            idx2[img * 2400 + oc * 25 + pos] = (u8)bi;
        }
    }
}

// ---------------- K3a: pre 1x1 conv (96->128) ----------------
__global__ __launch_bounds__(256) void k3a_pre(const float* __restrict__ z,
                                               const float* __restrict__ w,   // [128][96]
                                               const float* __restrict__ bias,
                                               float* __restrict__ vq) {
    const int img = blockIdx.x;
    const int tid = threadIdx.x;
    __shared__ float zs[2400];       // [96][25]
    __shared__ float pws[12288];     // [128][96]
    for (int i = tid; i < 2400; i += 256) zs[i] = z[img * 2400 + i];
    for (int i = tid; i < 12288; i += 256) pws[i] = w[i];
    __syncthreads();
    const int sg = tid % 5;
    const int eg = tid / 5;          // active if < 32
    if (eg >= 32) return;            // no more barriers below
    const int e0 = eg * 4, s0 = sg * 5;
    float acc[4][5];
#pragma unroll
    for (int j = 0; j < 4; ++j)
#pragma unroll
        for (int ss = 0; ss < 5; ++ss) acc[j][ss] = 0.f;
    for (int ci = 0; ci < 96; ++ci) {
        float zv[5];
#pragma unroll
        for (int ss = 0; ss < 5; ++ss) zv[ss] = zs[ci * 25 + s0 + ss];
#pragma unroll
        for (int j = 0; j < 4; ++j) {
            float wv = pws[(e0 + j) * 96 + ci];
#pragma unroll
            for (int ss = 0; ss < 5; ++ss) acc[j][ss] += wv * zv[ss];
        }
    }
#pragma unroll
    for (int j = 0; j < 4; ++j) {
        float bb = bias[e0 + j];
#pragma unroll
        for (int ss = 0; ss < 5; ++ss)
            vq[img * 3200 + (e0 + j) * 25 + s0 + ss] = acc[j][ss] + bb;
    }
}

// ---------------- K3b v2: VQ distances, code-chunked, broadcast LDS reads ----------------
// grid = 128 token-groups x 8 code-chunks. Block: 256 thr x 4 tokens in regs.
// Codebook chunk (128 codes x 28 floats, 16B-aligned rows) in LDS; all lanes read the
// same row per iteration -> pure broadcast, zero bank conflicts.
__global__ __launch_bounds__(256) void k3b_vq2(const float* __restrict__ vq,
                                               const float* __restrict__ cb,
                                               const float* __restrict__ cnorm,
                                               float* __restrict__ pbest,
                                               int* __restrict__ pbk) {
    const int tg = blockIdx.x >> 3;      // 0..127
    const int ch = blockIdx.x & 7;       // 0..7
    const int tid = threadIdx.x;
    const int k0 = ch * 128;
    __shared__ __align__(16) float cs[128 * 28];
    for (int i = tid; i < 128 * 28; i += 256) {
        int k = i / 28, d = i % 28;
        float v = 0.f;
        if (d < 25) v = cb[(k0 + k) * 25 + d];
        else if (d == 25) v = cnorm[k0 + k];
        cs[i] = v;
    }
    const int t0 = tg * 1024 + tid * 4;
    float f2[4][25];
#pragma unroll
    for (int t = 0; t < 4; ++t)
#pragma unroll
        for (int d = 0; d < 25; ++d)
            f2[t][d] = -2.f * vq[(t0 + t) * 25 + d];
    __syncthreads();
    float best[4] = {1e30f, 1e30f, 1e30f, 1e30f};
    int bk[4] = {0, 0, 0, 0};
    for (int k = 0; k < 128; ++k) {
        const float* crow = &cs[k * 28];
        float cc[28];
#pragma unroll
        for (int i = 0; i < 7; ++i)
            *(float4*)(cc + 4 * i) = *(const float4*)(crow + 4 * i);
        const float cn = cc[25];
        const int kg = k0 + k;
#pragma unroll
        for (int t = 0; t < 4; ++t) {
            float a = cn;
#pragma unroll
            for (int d = 0; d < 25; ++d) a = fmaf(f2[t][d], cc[d], a);
            // ascending k + strict < keeps FIRST (lowest-index) minimum
            if (a < best[t]) { best[t] = a; bk[t] = kg; }
        }
    }
#pragma unroll
    for (int t = 0; t < 4; ++t) {
        pbest[ch * 131072 + t0 + t] = best[t];
        pbk[ch * 131072 + t0 + t] = bk[t];
    }
}

// ---------------- K3r: merge 8 chunk-partials, write indices, loss partials ----------------
__global__ __launch_bounds__(256) void k3r_reduce(const float* __restrict__ pbest,
                                                  const int* __restrict__ pbk,
                                                  const float* __restrict__ vq,
                                                  int* __restrict__ vqidx,
                                                  float* __restrict__ lossacc) {
    const int t = blockIdx.x * 256 + threadIdx.x;   // 0..131071
    float best = 1e30f; int bk = 0;
#pragma unroll
    for (int ch = 0; ch < 8; ++ch) {
        float s = pbest[ch * 131072 + t];
        int k = pbk[ch * 131072 + t];
        // chunks are ascending code ranges; strict < keeps lowest global index on ties
        if (s < best) { best = s; bk = k; }
    }
    vqidx[t] = bk;
    float fn = 0.f;
#pragma unroll
    for (int d = 0; d < 25; ++d) { float v = vq[t * 25 + d]; fn = fmaf(v, v, fn); }
    float dloc = fn + best;   // ||f - c_best||^2
#pragma unroll
    for (int off = 32; off > 0; off >>= 1) dloc += __shfl_down(dloc, off, 64);
    __shared__ float wsum[4];
    if ((threadIdx.x & 63) == 0) wsum[threadIdx.x >> 6] = dloc;
    __syncthreads();
    if (threadIdx.x == 0)
        atomicAdd(lossacc, wsum[0] + wsum[1] + wsum[2] + wsum[3]);
}

// ---------------- Kf: finalize loss ----------------
__global__ void kf_loss(const float* __restrict__ lossacc, float* __restrict__ out) {
    out[0] = 0.25f * lossacc[0] / 3276800.0f;   // mean over B*128*25
}

// ---------------- K5: gather codebook, trans 1x1 (128->96) + pose head ----------------
__global__ __launch_bounds__(256) void k5_latent_pose(
    const int* __restrict__ vqidx, const float* __restrict__ cb,
    const float* __restrict__ tw, const float* __restrict__ tbb,
    const float* __restrict__ w1, const float* __restrict__ b1,
    const float* __restrict__ w2, const float* __restrict__ b2,
    float* __restrict__ latg, float* __restrict__ outkp) {
    const int img = blockIdx.x;
    const int tid = threadIdx.x;
    __shared__ int idxs[128];
    __shared__ float zr[128 * 26];   // padded
    __shared__ float lat[2400];      // [96][25] = feat layout
    __shared__ float ps[256];        // 8 segs x 32
    __shared__ float hs[32];
    if (tid < 128) idxs[tid] = vqidx[img * 128 + tid];
    __syncthreads();
    for (int i = tid; i < 3200; i += 256) {
        int e = i / 25, d = i % 25;
        zr[e * 26 + d] = cb[idxs[e] * 25 + d];
    }
    __syncthreads();
    const int sg = tid % 5, og = tid / 5;   // active og<24 (4 oc x 5 s each)
    if (og < 24) {
        const int oc0 = og * 4, s0 = sg * 5;
        float acc[4][5];
#pragma unroll
        for (int j = 0; j < 4; ++j)
#pragma unroll
            for (int ss = 0; ss < 5; ++ss) acc[j][ss] = 0.f;
        for (int e = 0; e < 128; ++e) {
            float zv[5];
#pragma unroll
            for (int ss = 0; ss < 5; ++ss) zv[ss] = zr[e * 26 + s0 + ss];
#pragma unroll
            for (int j = 0; j < 4; ++j) {
                float wv = tw[e * 96 + oc0 + j];
#pragma unroll
                for (int ss = 0; ss < 5; ++ss) acc[j][ss] += wv * zv[ss];
            }
        }
#pragma unroll
        for (int j = 0; j < 4; ++j) {
            float bb = tbb[oc0 + j];
#pragma unroll
            for (int ss = 0; ss < 5; ++ss) {
                float v = acc[j][ss] + bb;
                lat[(oc0 + j) * 25 + s0 + ss] = v;
                latg[img * 2400 + (oc0 + j) * 25 + s0 + ss] = v;
            }
        }
    }
    __syncthreads();
    // pose hidden partials: 8 segments x 32 hidden
    {
        const int seg = tid >> 5, jj = tid & 31;
        float s = 0.f;
        const int i0 = seg * 300;
        for (int i = i0; i < i0 + 300; ++i) s += lat[i] * w1[i * 32 + jj];
        ps[seg * 32 + jj] = s;
    }
    __syncthreads();
    if (tid < 32) {
        float h = b1[tid];
#pragma unroll
        for (int s2 = 0; s2 < 8; ++s2) h += ps[s2 * 32 + tid];
        hs[tid] = fmaxf(h, 0.f);
    }
    __syncthreads();
    if (tid < 36) {
        float kp = b2[tid];
#pragma unroll
        for (int m = 0; m < 32; ++m) kp += hs[m] * w2[m * 36 + tid];
        outkp[img * 36 + tid] = kp;
    }
}

// ---------------- K6: unpool(idx2) + dec1 conv3x3(96->32)+relu ----------------
__global__ __launch_bounds__(256) void k6_dec1(const float* __restrict__ latg,
                                               const u8* __restrict__ idx2,
                                               const float* __restrict__ w,   // [32][96][9]
                                               const float* __restrict__ bias,
                                               float* __restrict__ d1) {
    const int img = blockIdx.x;
    const int tid = threadIdx.x;
    __shared__ float u2s[9600];    // [96][10][10]
    __shared__ float w1s[4608];    // [32][16][9] ci-chunk
    for (int i = tid; i < 9600; i += 256) u2s[i] = 0.f;
    __syncthreads();
    for (int i = tid; i < 2400; i += 256) {
        int ci = i / 25, s = i % 25;
        int r = s / 5, c = s % 5;
        int q = idx2[img * 2400 + i];
        u2s[ci * 100 + (2 * r + (q >> 1)) * 10 + 2 * c + (q & 1)] = latg[img * 2400 + i];
    }
    const int quad = tid % 25, ocg = tid / 25;  // active ocg<8 (4 oc each)
    const int qr = quad / 5, qc = quad % 5;
    const int y0 = 2 * qr, x0 = 2 * qc;
    float acc[4][4];
#pragma unroll
    for (int j = 0; j < 4; ++j)
#pragma unroll
        for (int q = 0; q < 4; ++q) acc[j][q] = 0.f;
    for (int chunk = 0; chunk < 6; ++chunk) {
        __syncthreads();
        for (int i = tid; i < 4608; i += 256) {
            int oc = i / 144, rr = i % 144;
            int cc2 = rr / 9, kk = rr % 9;
            w1s[i] = w[(oc * 96 + chunk * 16 + cc2) * 9 + kk];
        }
        __syncthreads();
        if (ocg < 8) {
            for (int cil = 0; cil < 16; ++cil) {
                int ci = chunk * 16 + cil;
                float win[4][4];
#pragma unroll
                for (int wy = 0; wy < 4; ++wy) {
                    int yy = y0 - 1 + wy;
#pragma unroll
                    for (int wx = 0; wx < 4; ++wx) {
                        int xx = x0 - 1 + wx;
                        win[wy][wx] = (yy >= 0 && yy < 10 && xx >= 0 && xx < 10)
                                          ? u2s[ci * 100 + yy * 10 + xx] : 0.f;
                    }
                }
#pragma unroll
                for (int j = 0; j < 4; ++j) {
                    const float* wp = &w1s[(ocg * 4 + j) * 144 + cil * 9];
                    float wr[9];
#pragma unroll
                    for (int k = 0; k < 9; ++k) wr[k] = wp[k];
#pragma unroll
                    for (int q = 0; q < 4; ++q) {
                        int dr = q >> 1, dc = q & 1;
#pragma unroll
                        for (int ky = 0; ky < 3; ++ky)
#pragma unroll
                            for (int kx = 0; kx < 3; ++kx)
                                acc[j][q] += win[dr + ky][dc + kx] * wr[ky * 3 + kx];
                    }
                }
            }
        }
    }
    if (ocg < 8) {
#pragma unroll
        for (int j = 0; j < 4; ++j) {
            int oc = ocg * 4 + j;
            float bb = bias[oc];
#pragma unroll
            for (int q = 0; q < 4; ++q) {
                int dr = q >> 1, dc = q & 1;
                d1[img * 3200 + oc * 100 + (y0 + dr) * 10 + (x0 + dc)] =
                    fmaxf(acc[j][q] + bb, 0.f);
            }
        }
    }
}

// ---------------- K7: unpool(idx1) + dec2 conv3x3(32->3) -> r_x ----------------
__global__ __launch_bounds__(256) void k7_dec2(const float* __restrict__ d1,
                                               const u8* __restrict__ idx1,
                                               const float* __restrict__ w,   // [3][32][9]
                                               const float* __restrict__ bias,
                                               float* __restrict__ rx) {
    const int img = blockIdx.x;
    const int tid = threadIdx.x;
    __shared__ float u1s[12800];   // [32][20][20]
    __shared__ float wss[864];
    __shared__ float bss[3];
    for (int i = tid; i < 12800; i += 256) u1s[i] = 0.f;
    for (int i = tid; i < 864; i += 256) wss[i] = w[i];
    if (tid < 3) bss[tid] = bias[tid];
    __syncthreads();
    for (int i = tid; i < 3200; i += 256) {
        int c = i / 100, s = i % 100;
        int r = s / 10, cc = s % 10;
        int q = idx1[img * 3200 + i];
        u1s[c * 400 + (2 * r + (q >> 1)) * 20 + 2 * cc + (q & 1)] = d1[img * 3200 + i];
    }
    __syncthreads();
    if (tid < 200) {
        const int y = tid / 10, px = tid % 10;
        const int x0 = px * 2;
        float acc[3][2] = {{0.f, 0.f}, {0.f, 0.f}, {0.f, 0.f}};
        for (int ci = 0; ci < 32; ++ci) {
            float win[3][4];
#pragma unroll
            for (int wy = 0; wy < 3; ++wy) {
                int yy = y - 1 + wy;
#pragma unroll
                for (int wx = 0; wx < 4; ++wx) {
                    int xx = x0 - 1 + wx;
                    win[wy][wx] = (yy >= 0 && yy < 20 && xx >= 0 && xx < 20)
                                      ? u1s[ci * 400 + yy * 20 + xx] : 0.f;
                }
            }
#pragma unroll
            for (int oc = 0; oc < 3; ++oc) {
                const float* wp = &wss[(oc * 32 + ci) * 9];
                float wr[9];
#pragma unroll
                for (int k = 0; k < 9; ++k) wr[k] = wp[k];
#pragma unroll
                for (int ky = 0; ky < 3; ++ky)
#pragma unroll
                    for (int kx = 0; kx < 3; ++kx) {
                        acc[oc][0] += win[ky][kx] * wr[ky * 3 + kx];
                        acc[oc][1] += win[ky][kx + 1] * wr[ky * 3 + kx];
                    }
            }
        }
#pragma unroll
        for (int oc = 0; oc < 3; ++oc) {
#pragma unroll
            for (int dx = 0; dx < 2; ++dx)
                rx[img * 1200 + oc * 400 + y * 20 + x0 + dx] = acc[oc][dx] + bss[oc];
        }
    }
}

extern "C" void kernel_launch(void* const* d_in, const int* in_sizes, int n_in,
                              void* d_out, int out_size, void* d_ws, size_t ws_size,
                              hipStream_t stream) {
    const float* x   = (const float*)d_in[0];
    const float* e1w = (const float*)d_in[1];
    const float* e1b = (const float*)d_in[2];
    const float* e2w = (const float*)d_in[3];
    const float* e2b = (const float*)d_in[4];
    const float* prw = (const float*)d_in[5];
    const float* prb = (const float*)d_in[6];
    const float* cb  = (const float*)d_in[7];
    const float* tw  = (const float*)d_in[8];
    const float* tbb = (const float*)d_in[9];
    const float* d1w = (const float*)d_in[10];
    const float* d1b = (const float*)d_in[11];
    const float* d2w = (const float*)d_in[12];
    const float* d2b = (const float*)d_in[13];
    const float* hw1 = (const float*)d_in[14];
    const float* hb1 = (const float*)d_in[15];
    const float* hw2 = (const float*)d_in[16];
    const float* hb2 = (const float*)d_in[17];
    float* out = (float*)d_out;

    // workspace layout (fp32 unless noted); buffers reused where lifetimes allow
    float* ws      = (float*)d_ws;
    float* cnorm   = ws;                        // 1024
    float* lossacc = cnorm + 1024;              // 4
    float* p1      = lossacc + 4;               // 3,276,800 (reused as latent after K2)
    float* z       = p1 + 3276800;              // 2,457,600 (dead after K3a -> pbest/pbk overlay)
    float* vq      = z + 2457600;               // 3,276,800 (reused as d1 after K3r)
    int*   vqidx   = (int*)(vq + 3276800);      // 131,072
    u8*    idx1    = (u8*)(vqidx + 131072);     // 3,276,800 bytes
    u8*    idx2    = idx1 + 3276800;            // 2,457,600 bytes
    float* latent  = p1;
    float* d1buf   = vq;
    float* pbest   = z;                         // 8*131072 = 1,048,576 floats
    int*   pbk     = (int*)(z + 1048576);       // 8*131072 = 1,048,576 ints (fits in z's 2.46M)

    float* rx  = out + 1;
    float* okp = out + 1 + 1228800;

    k0_cnorm<<<4, 256, 0, stream>>>(cb, cnorm, lossacc);
    k1_enc1<<<1024, 256, 0, stream>>>(x, e1w, e1b, p1, idx1);
    k2_enc2<<<1024, 256, 0, stream>>>(p1, e2w, e2b, z, idx2);
    k3a_pre<<<1024, 256, 0, stream>>>(z, prw, prb, vq);
    k3b_vq2<<<1024, 256, 0, stream>>>(vq, cb, cnorm, pbest, pbk);
    k3r_reduce<<<512, 256, 0, stream>>>(pbest, pbk, vq, vqidx, lossacc);
    kf_loss<<<1, 1, 0, stream>>>(lossacc, out);
    k5_latent_pose<<<1024, 256, 0, stream>>>(vqidx, cb, tw, tbb, hw1, hb1, hw2, hb2,
                                             latent, okp);
    k6_dec1<<<1024, 256, 0, stream>>>(latent, idx2, d1w, d1b, d1buf);
    k7_dec2<<<1024, 256, 0, stream>>>(d1buf, idx1, d2w, d2b, rx);
}